// Round 1
// 242.718 us; speedup vs baseline: 1.0444x; 1.0444x over previous
//
#include <hip/hip_runtime.h>

typedef __bf16 bf16;
typedef __bf16 bf16x4 __attribute__((ext_vector_type(4)));
typedef __bf16 bf16x8 __attribute__((ext_vector_type(8)));
typedef float f32x4 __attribute__((ext_vector_type(4)));

#define NROWS 32768   // B*S = 32*1024
#define EMBED 512
#define CONV_C 512
#define HID 1024
#define LABELS 128

__device__ inline void async16(const void* g, void* l) {
  __builtin_amdgcn_global_load_lds(
      (const __attribute__((address_space(1))) void*)g,
      (__attribute__((address_space(3))) void*)l, 16, 0, 0);
}

// swap bits 0 and 2 of a small value (involution)
__device__ inline int bitswap02(int g) {
  return ((g & 1) << 2) | (g & 0xA) | ((g >> 2) & 1);
}

// two 16B fp32 chunks (swizzled positions) -> bf16x8 fragment
__device__ inline bf16x8 cvt8_sw(const float* row, int o0, int o1) {
  f32x4 lo = *(const f32x4*)(row + o0);
  f32x4 hi = *(const f32x4*)(row + o1);
  bf16x8 r;
  r[0] = (bf16)lo[0]; r[1] = (bf16)lo[1]; r[2] = (bf16)lo[2]; r[3] = (bf16)lo[3];
  r[4] = (bf16)hi[0]; r[5] = (bf16)hi[1]; r[6] = (bf16)hi[2]; r[7] = (bf16)hi[3];
  return r;
}

// ---- prep kernels ----------------------------------------------------------

__global__ void cvt_bf16(const float* __restrict__ in, bf16* __restrict__ out, int n) {
  int i = (blockIdx.x * blockDim.x + threadIdx.x) * 4;
  if (i >= n) return;
  float4 v = *(const float4*)(in + i);
  bf16x4 o;
  o.x = (bf16)v.x; o.y = (bf16)v.y; o.z = (bf16)v.z; o.w = (bf16)v.w;
  *(bf16x4*)(out + i) = o;
}

// [K,N] f32 -> [N,K] bf16 transpose, 64x64 tiles
__global__ void transpose_cvt(const float* __restrict__ in, bf16* __restrict__ out,
                              int K, int N) {
  __shared__ float t[64][65];
  int kb = blockIdx.x * 64, nb = blockIdx.y * 64;
  for (int i = threadIdx.x; i < 4096; i += 256) {
    int r = i >> 6, c = i & 63;
    t[r][c] = in[(size_t)(kb + r) * N + nb + c];
  }
  __syncthreads();
  for (int i = threadIdx.x; i < 4096; i += 256) {
    int r = i >> 6, c = i & 63;
    out[(size_t)(nb + r) * K + kb + c] = (bf16)t[c][r];
  }
}

// ---- layer 1: h = relu(emb[tok] @ conv_w^T + conv_b) -----------------------
// (unchanged this round)
__global__ __launch_bounds__(256) void gemm1_gather(
    const int* __restrict__ tok, const float* __restrict__ emb,
    const bf16* __restrict__ convw, const float* __restrict__ bias,
    bf16* __restrict__ out, int M, int N, int K) {
  __shared__ __attribute__((aligned(16))) char smem[49152];
  const int tid = threadIdx.x;
  const int wave = tid >> 6, lane = tid & 63;
  const int m0 = blockIdx.x * 128, n0 = blockIdx.y * 128;
  const int wm = (wave & 1) * 64, wn = (wave >> 1) * 64;
  const int lrow = lane & 15, quad = lane >> 4;
  const int slot0 = wave * 64 + lane;

  int arow[4], acol[4];
#pragma unroll
  for (int c = 0; c < 4; ++c) {
    int s = slot0 + c * 256;
    int r = s >> 3, p = s & 7;
    arow[c] = r;
    acol[c] = (p ^ (r & 7)) * 4;
  }
  int trow[4];
#pragma unroll
  for (int c = 0; c < 4; ++c) trow[c] = tok[m0 + arow[c]];

  const f32x4 zero4 = {0.f, 0.f, 0.f, 0.f};
  f32x4 acc[4][4];
#pragma unroll
  for (int i = 0; i < 4; ++i)
#pragma unroll
    for (int j = 0; j < 4; ++j) acc[i][j] = zero4;

  auto stage = [&](int p, int k0) {
    float* lAf = (float*)(smem + p * 24576);
    bf16* lB = (bf16*)(smem + p * 24576 + 16384);
#pragma unroll
    for (int c = 0; c < 4; ++c)
      async16(emb + (size_t)trow[c] * EMBED + k0 + acol[c],
              lAf + (size_t)(wave * 64 + c * 256) * 4);
#pragma unroll
    for (int c = 0; c < 2; ++c) {
      int s = slot0 + c * 256;
      int r = s >> 2, cs = s & 3;
      async16(convw + (size_t)(n0 + r) * K + k0 + cs * 8,
              lB + (size_t)(wave * 64 + c * 256) * 8);
    }
  };

  stage(0, 0);
  int cur = 0;
  for (int it = 0; it < 16; ++it) {
    __syncthreads();
    if (it < 15) stage(cur ^ 1, (it + 1) * 32);
    const float* lAf = (const float*)(smem + cur * 24576);
    const bf16* lB = (const bf16*)(smem + cur * 24576 + 16384);

    bf16x8 a[4], b[4];
#pragma unroll
    for (int t = 0; t < 4; ++t) {
      int r = wm + t * 16 + lrow, sw = r & 7;
      a[t] = cvt8_sw(lAf + r * 32, ((2 * quad) ^ sw) * 4, ((2 * quad + 1) ^ sw) * 4);
      b[t] = *(const bf16x8*)(lB + (wn + t * 16 + lrow) * 32 + quad * 8);
    }
#pragma unroll
    for (int mi = 0; mi < 4; ++mi)
#pragma unroll
      for (int ni = 0; ni < 4; ++ni)
        acc[mi][ni] =
            __builtin_amdgcn_mfma_f32_16x16x32_bf16(a[mi], b[ni], acc[mi][ni], 0, 0, 0);
    cur ^= 1;
  }

#pragma unroll
  for (int mi = 0; mi < 4; ++mi) {
#pragma unroll
    for (int ni = 0; ni < 4; ++ni) {
      int col = n0 + wn + ni * 16 + lrow;
      float bv = bias[col];
#pragma unroll
      for (int r = 0; r < 4; ++r) {
        int row = m0 + wm + mi * 16 + quad * 4 + r;
        float v = acc[mi][ni][r] + bv;
        v = v > 0.f ? v : 0.f;
        out[(size_t)row * N + col] = (bf16)v;
      }
    }
  }
}

// ---- fused layers 2+3 (v4: 8-wave 128-row blocks, 64x64 wave tiles) --------
// Grid 256 blocks (1/CU), 512 threads. z in 4 chunks of N=256.
// LDS map (128 KB total):
//   [0,      32K)  A0,A1: h tile [128 x 64] bf16, 16 KB each (double buffer)
//   [32K,    96K)  B0,B1: w1t tile [256 x 64] bf16, 32 KB each (double buffer)
//                  zbuf [128 x 256] bf16 (64 KB) ALIASES B0+B1 (dead at z-time)
//   [96K,   128K)  lB3 ping-pong: 2 x [128 x 64] bf16 (w2t quarter, 16 KB each)
// Staging: linear LDS dest, source col pre-swizzled with (slot^row)&7 so that
// ds_read at pos = (k/8)^(row&7) is conflict-free (proven pattern, 0 conflicts).
// zbuf uses pos = (col/8) ^ bitswap02(row&7) on both write and read sides.
__global__ __launch_bounds__(512, 2) void gemm23_fused(
    const bf16* __restrict__ h,     // [32768, 512]
    const bf16* __restrict__ w1t,   // [1024, 512]
    const bf16* __restrict__ w2t,   // [128, 1024]
    const float* __restrict__ b1, const float* __restrict__ b2,
    float* __restrict__ out) {
  __shared__ __attribute__((aligned(16))) char smem[131072];
  bf16* zbuf = (bf16*)(smem + 32768);
  const int tid = threadIdx.x, wave = tid >> 6, lane = tid & 63;
  const int m0 = blockIdx.x * 128;
  const int am0 = (wave >> 2) * 64;   // wave m-offset (layers 2 and 3)
  const int bn0 = (wave & 3) * 64;    // wave n-offset within z-chunk
  const int lb0 = (wave & 3) * 32;    // wave label-offset (layer 3)
  const int lrow = lane & 15, quad = lane >> 4;
  const int lsw = lrow & 7;           // row&7 for all fragment rows
  const int bsw = bitswap02(lsw);     // zbuf read mask

  // staging geometry: slot s -> row = s>>3, src col = ((s&7)^(row&7))*8
  int a_r[2], a_c[2];
#pragma unroll
  for (int c = 0; c < 2; ++c) {
    int s = tid + c * 512;
    a_r[c] = s >> 3;
    a_c[c] = ((s & 7) ^ (a_r[c] & 7)) * 8;
  }
  int b_r[4], b_c[4];
#pragma unroll
  for (int c = 0; c < 4; ++c) {
    int s = tid + c * 512;
    b_r[c] = s >> 3;
    b_c[c] = ((s & 7) ^ (b_r[c] & 7)) * 8;
  }
  int q_r[2], q_c[2];
#pragma unroll
  for (int c = 0; c < 2; ++c) {
    int s = tid + c * 512;
    q_r[c] = s >> 3;
    q_c[c] = ((s & 7) ^ (q_r[c] & 7)) * 8;
  }

  auto stageA = [&](int p, int k0) {
    bf16* lA = (bf16*)(smem + p * 16384);
#pragma unroll
    for (int c = 0; c < 2; ++c)
      async16(h + (size_t)(m0 + a_r[c]) * 512 + k0 + a_c[c],
              lA + (size_t)(tid + c * 512) * 8);
  };
  auto stageB = [&](int p, int cn0, int k0) {
    bf16* lB = (bf16*)(smem + 32768 + p * 32768);
#pragma unroll
    for (int c = 0; c < 4; ++c)
      async16(w1t + (size_t)(cn0 + b_r[c]) * 512 + k0 + b_c[c],
              lB + (size_t)(tid + c * 512) * 8);
  };
  auto stageQ = [&](int cn0, int qq, int pq) {
    bf16* lQ = (bf16*)(smem + 98304 + pq * 16384);
#pragma unroll
    for (int c = 0; c < 2; ++c)
      async16(w2t + (size_t)q_r[c] * HID + cn0 + qq * 64 + q_c[c],
              lQ + (size_t)(tid + c * 512) * 8);
  };

  const f32x4 zero4 = {0.f, 0.f, 0.f, 0.f};
  f32x4 out_acc[4][2];
#pragma unroll
  for (int i = 0; i < 4; ++i)
#pragma unroll
    for (int j = 0; j < 2; ++j) out_acc[i][j] = zero4;

  auto layer3 = [&](int qq, int pq) {
    const bf16* lQ = (const bf16*)(smem + 98304 + pq * 16384);
#pragma unroll
    for (int ks = 0; ks < 2; ++ks) {
      bf16x8 a3[4], b3[2];
#pragma unroll
      for (int t = 0; t < 4; ++t) {
        int m = am0 + t * 16 + lrow;
        int kq = qq * 8 + ks * 4 + quad;   // k/8 within the 256-wide chunk
        a3[t] = *(const bf16x8*)(zbuf + m * 256 + ((kq ^ bsw) << 3));
      }
#pragma unroll
      for (int t = 0; t < 2; ++t) {
        int lab = lb0 + t * 16 + lrow;
        b3[t] = *(const bf16x8*)(lQ + lab * 64 + (((ks * 4 + quad) ^ lsw) * 8));
      }
#pragma unroll
      for (int mi = 0; mi < 4; ++mi)
#pragma unroll
        for (int ni = 0; ni < 2; ++ni)
          out_acc[mi][ni] =
              __builtin_amdgcn_mfma_f32_16x16x32_bf16(a3[mi], b3[ni], out_acc[mi][ni], 0, 0, 0);
    }
  };

  for (int chunk = 0; chunk < 4; ++chunk) {
    const int cn0 = chunk * 256;
    // prologue staging (A for chunk>0 was prefetched during prev layer3)
    if (chunk == 0) stageA(0, 0);
    stageB(0, cn0, 0);
    stageQ(cn0, 0, 0);

    f32x4 z_acc[4][4];
#pragma unroll
    for (int i = 0; i < 4; ++i)
#pragma unroll
      for (int j = 0; j < 4; ++j) z_acc[i][j] = zero4;

    int cur = 0;
    for (int it = 0; it < 8; ++it) {
      __syncthreads();                  // buf[cur] staged; prior reads fenced
      if (it < 7) {
        stageB(cur ^ 1, cn0, (it + 1) * 64);
        stageA(cur ^ 1, (it + 1) * 64);
      }
      const bf16* lA = (const bf16*)(smem + cur * 16384);
      const bf16* lB = (const bf16*)(smem + 32768 + cur * 32768);
#pragma unroll
      for (int ks = 0; ks < 2; ++ks) {
        bf16x8 a[4], b[4];
#pragma unroll
        for (int t = 0; t < 4; ++t)
          a[t] = *(const bf16x8*)(lA + (am0 + t * 16 + lrow) * 64 +
                                  (((ks * 4 + quad) ^ lsw) * 8));
#pragma unroll
        for (int t = 0; t < 4; ++t)
          b[t] = *(const bf16x8*)(lB + (bn0 + t * 16 + lrow) * 64 +
                                  (((ks * 4 + quad) ^ lsw) * 8));
#pragma unroll
        for (int mi = 0; mi < 4; ++mi)
#pragma unroll
          for (int ni = 0; ni < 4; ++ni)
            z_acc[mi][ni] =
                __builtin_amdgcn_mfma_f32_16x16x32_bf16(a[mi], b[ni], z_acc[mi][ni], 0, 0, 0);
      }
      cur ^= 1;
    }

    __syncthreads();                    // (a) all K-loop reads fenced; B bufs dead
    stageQ(cn0, 1, 1);                  // w2 quarter 1 -> pp1 (under z-write)
    // z-write (bias + relu, bf16) into swizzled zbuf (aliases B bufs)
#pragma unroll
    for (int mi = 0; mi < 4; ++mi) {
#pragma unroll
      for (int ni = 0; ni < 4; ++ni) {
        int zcol = bn0 + ni * 16 + lrow;
        float bv = b1[cn0 + zcol];
        int q5 = zcol >> 3;
#pragma unroll
        for (int r = 0; r < 4; ++r) {
          int zrow = am0 + mi * 16 + quad * 4 + r;
          float v = z_acc[mi][ni][r] + bv;
          v = v > 0.f ? v : 0.f;
          zbuf[zrow * 256 + ((q5 ^ bitswap02(zrow & 7)) << 3) + (zcol & 7)] = (bf16)v;
        }
      }
    }
    __syncthreads();                    // (b) z visible; q0/q1 staged
    layer3(0, 0);
    __syncthreads();                    // (c) pp0 reads done
    stageQ(cn0, 2, 0);                  // q2 -> pp0 (under layer3 q1)
    layer3(1, 1);
    __syncthreads();                    // (d) pp1 reads done; q2 landed
    stageQ(cn0, 3, 1);                  // q3 -> pp1 (under layer3 q2)
    if (chunk < 3) stageA(0, 0);        // prefetch next chunk's first A tile
    layer3(2, 0);
    __syncthreads();                    // (e) pp0 reads done; q3 + A landed
    layer3(3, 1);
    __syncthreads();                    // (f) all zbuf reads done -> next chunk
  }

  // epilogue: out = out_acc + b2
#pragma unroll
  for (int mi = 0; mi < 4; ++mi) {
#pragma unroll
    for (int ni = 0; ni < 2; ++ni) {
      int col = lb0 + ni * 16 + lrow;
      float bv = b2[col];
#pragma unroll
      for (int r = 0; r < 4; ++r) {
        int row = m0 + am0 + mi * 16 + quad * 4 + r;
        out[(size_t)row * LABELS + col] = out_acc[mi][ni][r] + bv;
      }
    }
  }
}

// ---- launcher --------------------------------------------------------------

extern "C" void kernel_launch(void* const* d_in, const int* in_sizes, int n_in,
                              void* d_out, int out_size, void* d_ws, size_t ws_size,
                              hipStream_t stream) {
  const int* tok = (const int*)d_in[0];
  const float* emb = (const float*)d_in[1];
  const float* conv_w = (const float*)d_in[2];  // [512,512] = [N,K]
  const float* conv_b = (const float*)d_in[3];
  const float* w1 = (const float*)d_in[4];      // [512,1024] = [K,N]
  const float* b1 = (const float*)d_in[5];
  const float* w2 = (const float*)d_in[6];      // [1024,128] = [K,N]
  const float* b2 = (const float*)d_in[7];
  float* out = (float*)d_out;

  char* ws = (char*)d_ws;
  bf16* wtc = (bf16*)(ws);                       // 512 KB [512,512]
  bf16* wt1 = (bf16*)(ws + (1u << 19));          // 1 MB   [1024,512]
  bf16* wt2 = (bf16*)(ws + 3 * (1u << 19));      // 256 KB [128,1024]
  bf16* h = (bf16*)(ws + (2u << 20));            // 32 MB  [32768,512]

  // weight prep
  hipLaunchKernelGGL(cvt_bf16, dim3(256), dim3(256), 0, stream,
                     conv_w, wtc, CONV_C * EMBED);
  hipLaunchKernelGGL(transpose_cvt, dim3(8, 16), dim3(256), 0, stream,
                     w1, wt1, CONV_C, HID);
  hipLaunchKernelGGL(transpose_cvt, dim3(16, 2), dim3(256), 0, stream,
                     w2, wt2, HID, LABELS);

  // layer 1 (gather fused, double-buffered)
  hipLaunchKernelGGL(gemm1_gather, dim3(NROWS / 128, CONV_C / 128), dim3(256),
                     0, stream, tok, emb, wtc, conv_b, h, NROWS, CONV_C, EMBED);
  // layers 2+3 fused (v4: 128-row blocks, 8 waves, 64x64 wave tiles)
  hipLaunchKernelGGL(gemm23_fused, dim3(NROWS / 128), dim3(512),
                     0, stream, h, wt1, wt2, b1, b2, out);
}

// Round 2
// 237.084 us; speedup vs baseline: 1.0692x; 1.0238x over previous
//
#include <hip/hip_runtime.h>

typedef __bf16 bf16;
typedef __bf16 bf16x4 __attribute__((ext_vector_type(4)));
typedef __bf16 bf16x8 __attribute__((ext_vector_type(8)));
typedef float f32x4 __attribute__((ext_vector_type(4)));

#define NROWS 32768   // B*S = 32*1024
#define EMBED 512
#define CONV_C 512
#define HID 1024
#define LABELS 128

__device__ inline void async16(const void* g, void* l) {
  __builtin_amdgcn_global_load_lds(
      (const __attribute__((address_space(1))) void*)g,
      (__attribute__((address_space(3))) void*)l, 16, 0, 0);
}

// swap bits 0 and 2 of a small value (involution)
__device__ inline int bitswap02(int g) {
  return ((g & 1) << 2) | (g & 0xA) | ((g >> 2) & 1);
}

// two 16B fp32 chunks (swizzled positions) -> bf16x8 fragment
__device__ inline bf16x8 cvt8_sw(const float* row, int o0, int o1) {
  f32x4 lo = *(const f32x4*)(row + o0);
  f32x4 hi = *(const f32x4*)(row + o1);
  bf16x8 r;
  r[0] = (bf16)lo[0]; r[1] = (bf16)lo[1]; r[2] = (bf16)lo[2]; r[3] = (bf16)lo[3];
  r[4] = (bf16)hi[0]; r[5] = (bf16)hi[1]; r[6] = (bf16)hi[2]; r[7] = (bf16)hi[3];
  return r;
}

// ---- prep kernels ----------------------------------------------------------

__global__ void cvt_bf16(const float* __restrict__ in, bf16* __restrict__ out, int n) {
  int i = (blockIdx.x * blockDim.x + threadIdx.x) * 4;
  if (i >= n) return;
  float4 v = *(const float4*)(in + i);
  bf16x4 o;
  o.x = (bf16)v.x; o.y = (bf16)v.y; o.z = (bf16)v.z; o.w = (bf16)v.w;
  *(bf16x4*)(out + i) = o;
}

// [K,N] f32 -> [N,K] bf16 transpose, 64x64 tiles
__global__ void transpose_cvt(const float* __restrict__ in, bf16* __restrict__ out,
                              int K, int N) {
  __shared__ float t[64][65];
  int kb = blockIdx.x * 64, nb = blockIdx.y * 64;
  for (int i = threadIdx.x; i < 4096; i += 256) {
    int r = i >> 6, c = i & 63;
    t[r][c] = in[(size_t)(kb + r) * N + nb + c];
  }
  __syncthreads();
  for (int i = threadIdx.x; i < 4096; i += 256) {
    int r = i >> 6, c = i & 63;
    out[(size_t)(nb + r) * K + kb + c] = (bf16)t[c][r];
  }
}

// ---- layer 1 v2: h = relu(emb[tok] @ conv_w^T + conv_b) --------------------
// 8-wave 128-row blocks (grid 256 = 1/CU), N=512 in 2 chunks of 256, K-step 64.
// Kills the old 4x n-grid emb re-fetch and the 8-way B-read bank conflict.
// LDS map (128 KB):
//   [0,   64K)  A0,A1: emb tile [128 x 64] f32, 32 KB each (double buffer)
//   [64K,128K)  B0,B1: convw tile [256 x 64] bf16, 32 KB each (double buffer)
// A swizzle: rows of 64 f32 = 16 chunks of 16B; LDS pos p holds src chunk
//   ((p&7)^(row&7)) | (p&8)  -> read pos = (cc&8) | ((cc&7)^(row&7)), 2-way free.
// B swizzle: identical to gemm23's proven pattern (128B rows, 8-pos XOR).
__global__ __launch_bounds__(512, 2) void gemm1_gather(
    const int* __restrict__ tok, const float* __restrict__ emb,
    const bf16* __restrict__ convw, const float* __restrict__ bias,
    bf16* __restrict__ out, int M, int N, int K) {
  __shared__ __attribute__((aligned(16))) char smem[131072];
  const int tid = threadIdx.x, wave = tid >> 6, lane = tid & 63;
  const int m0 = blockIdx.x * 128;
  const int am0 = (wave >> 2) * 64;   // wave m-offset
  const int bn0 = (wave & 3) * 64;    // wave n-offset within 256-chunk
  const int lrow = lane & 15, quad = lane >> 4;

  // A staging geometry: 4 chunks of 512 slots; slot s -> row s>>4, p = s&15
  int a_r[4], a_c[4];
#pragma unroll
  for (int c = 0; c < 4; ++c) {
    int s = tid + c * 512;
    int r = s >> 4, p = s & 15;
    a_r[c] = r;
    a_c[c] = ((((p & 7) ^ (r & 7)) | (p & 8))) * 4;   // src f32 col
  }
  int trow[4];
#pragma unroll
  for (int c = 0; c < 4; ++c) trow[c] = tok[m0 + a_r[c]];

  // B staging geometry: 4 chunks; slot s -> row s>>3, src col ((s&7)^(r&7))*8
  int b_r[4], b_c[4];
#pragma unroll
  for (int c = 0; c < 4; ++c) {
    int s = tid + c * 512;
    b_r[c] = s >> 3;
    b_c[c] = ((s & 7) ^ (b_r[c] & 7)) * 8;
  }

  auto stageA = [&](int p, int k0) {
    float* lAf = (float*)(smem + p * 32768);
#pragma unroll
    for (int c = 0; c < 4; ++c)
      async16(emb + (size_t)trow[c] * EMBED + k0 + a_c[c],
              lAf + (size_t)(tid + c * 512) * 4);
  };
  auto stageB = [&](int p, int cn0, int k0) {
    bf16* lB = (bf16*)(smem + 65536 + p * 32768);
#pragma unroll
    for (int c = 0; c < 4; ++c)
      async16(convw + (size_t)(cn0 + b_r[c]) * EMBED + k0 + b_c[c],
              lB + (size_t)(tid + c * 512) * 8);
  };

  const f32x4 zero4 = {0.f, 0.f, 0.f, 0.f};

  for (int chunk = 0; chunk < 2; ++chunk) {
    const int cn0 = chunk * 256;
    stageA(0, 0);
    stageB(0, cn0, 0);

    f32x4 acc[4][4];
#pragma unroll
    for (int i = 0; i < 4; ++i)
#pragma unroll
      for (int j = 0; j < 4; ++j) acc[i][j] = zero4;

    int cur = 0;
    for (int it = 0; it < 8; ++it) {
      __syncthreads();                  // buf[cur] staged; prior reads fenced
      if (it < 7) {
        stageA(cur ^ 1, (it + 1) * 64);
        stageB(cur ^ 1, cn0, (it + 1) * 64);
      }
      const float* lAf = (const float*)(smem + cur * 32768);
      const bf16* lB = (const bf16*)(smem + 65536 + cur * 32768);
#pragma unroll
      for (int ks = 0; ks < 2; ++ks) {
        bf16x8 a[4], b[4];
#pragma unroll
        for (int t = 0; t < 4; ++t) {
          int r = am0 + t * 16 + lrow, sw = r & 7;
          int p0 = ks * 8 + ((2 * quad) ^ sw);
          int p1 = ks * 8 + ((2 * quad + 1) ^ sw);
          a[t] = cvt8_sw(lAf + r * 64, p0 * 4, p1 * 4);
        }
#pragma unroll
        for (int t = 0; t < 4; ++t) {
          int rn = bn0 + t * 16 + lrow;
          b[t] = *(const bf16x8*)(lB + rn * 64 + (((ks * 4 + quad) ^ (rn & 7)) * 8));
        }
#pragma unroll
        for (int mi = 0; mi < 4; ++mi)
#pragma unroll
          for (int ni = 0; ni < 4; ++ni)
            acc[mi][ni] =
                __builtin_amdgcn_mfma_f32_16x16x32_bf16(a[mi], b[ni], acc[mi][ni], 0, 0, 0);
      }
      cur ^= 1;
    }

    // epilogue: bias + relu -> h (bf16). Safe to overlap next chunk's staging:
    // all buf0 readers passed the it=7 barrier before any wave reaches it.
#pragma unroll
    for (int mi = 0; mi < 4; ++mi) {
#pragma unroll
      for (int ni = 0; ni < 4; ++ni) {
        int col = cn0 + bn0 + ni * 16 + lrow;
        float bv = bias[col];
#pragma unroll
        for (int r = 0; r < 4; ++r) {
          int row = m0 + am0 + mi * 16 + quad * 4 + r;
          float v = acc[mi][ni][r] + bv;
          v = v > 0.f ? v : 0.f;
          out[(size_t)row * CONV_C + col] = (bf16)v;
        }
      }
    }
  }
}

// ---- fused layers 2+3 (v4: 8-wave 128-row blocks, 64x64 wave tiles) --------
// (unchanged this round)
__global__ __launch_bounds__(512, 2) void gemm23_fused(
    const bf16* __restrict__ h,     // [32768, 512]
    const bf16* __restrict__ w1t,   // [1024, 512]
    const bf16* __restrict__ w2t,   // [128, 1024]
    const float* __restrict__ b1, const float* __restrict__ b2,
    float* __restrict__ out) {
  __shared__ __attribute__((aligned(16))) char smem[131072];
  bf16* zbuf = (bf16*)(smem + 32768);
  const int tid = threadIdx.x, wave = tid >> 6, lane = tid & 63;
  const int m0 = blockIdx.x * 128;
  const int am0 = (wave >> 2) * 64;   // wave m-offset (layers 2 and 3)
  const int bn0 = (wave & 3) * 64;    // wave n-offset within z-chunk
  const int lb0 = (wave & 3) * 32;    // wave label-offset (layer 3)
  const int lrow = lane & 15, quad = lane >> 4;
  const int lsw = lrow & 7;           // row&7 for all fragment rows
  const int bsw = bitswap02(lsw);     // zbuf read mask

  int a_r[2], a_c[2];
#pragma unroll
  for (int c = 0; c < 2; ++c) {
    int s = tid + c * 512;
    a_r[c] = s >> 3;
    a_c[c] = ((s & 7) ^ (a_r[c] & 7)) * 8;
  }
  int b_r[4], b_c[4];
#pragma unroll
  for (int c = 0; c < 4; ++c) {
    int s = tid + c * 512;
    b_r[c] = s >> 3;
    b_c[c] = ((s & 7) ^ (b_r[c] & 7)) * 8;
  }
  int q_r[2], q_c[2];
#pragma unroll
  for (int c = 0; c < 2; ++c) {
    int s = tid + c * 512;
    q_r[c] = s >> 3;
    q_c[c] = ((s & 7) ^ (q_r[c] & 7)) * 8;
  }

  auto stageA = [&](int p, int k0) {
    bf16* lA = (bf16*)(smem + p * 16384);
#pragma unroll
    for (int c = 0; c < 2; ++c)
      async16(h + (size_t)(m0 + a_r[c]) * 512 + k0 + a_c[c],
              lA + (size_t)(tid + c * 512) * 8);
  };
  auto stageB = [&](int p, int cn0, int k0) {
    bf16* lB = (bf16*)(smem + 32768 + p * 32768);
#pragma unroll
    for (int c = 0; c < 4; ++c)
      async16(w1t + (size_t)(cn0 + b_r[c]) * 512 + k0 + b_c[c],
              lB + (size_t)(tid + c * 512) * 8);
  };
  auto stageQ = [&](int cn0, int qq, int pq) {
    bf16* lQ = (bf16*)(smem + 98304 + pq * 16384);
#pragma unroll
    for (int c = 0; c < 2; ++c)
      async16(w2t + (size_t)q_r[c] * HID + cn0 + qq * 64 + q_c[c],
              lQ + (size_t)(tid + c * 512) * 8);
  };

  const f32x4 zero4 = {0.f, 0.f, 0.f, 0.f};
  f32x4 out_acc[4][2];
#pragma unroll
  for (int i = 0; i < 4; ++i)
#pragma unroll
    for (int j = 0; j < 2; ++j) out_acc[i][j] = zero4;

  auto layer3 = [&](int qq, int pq) {
    const bf16* lQ = (const bf16*)(smem + 98304 + pq * 16384);
#pragma unroll
    for (int ks = 0; ks < 2; ++ks) {
      bf16x8 a3[4], b3[2];
#pragma unroll
      for (int t = 0; t < 4; ++t) {
        int m = am0 + t * 16 + lrow;
        int kq = qq * 8 + ks * 4 + quad;   // k/8 within the 256-wide chunk
        a3[t] = *(const bf16x8*)(zbuf + m * 256 + ((kq ^ bsw) << 3));
      }
#pragma unroll
      for (int t = 0; t < 2; ++t) {
        int lab = lb0 + t * 16 + lrow;
        b3[t] = *(const bf16x8*)(lQ + lab * 64 + (((ks * 4 + quad) ^ lsw) * 8));
      }
#pragma unroll
      for (int mi = 0; mi < 4; ++mi)
#pragma unroll
        for (int ni = 0; ni < 2; ++ni)
          out_acc[mi][ni] =
              __builtin_amdgcn_mfma_f32_16x16x32_bf16(a3[mi], b3[ni], out_acc[mi][ni], 0, 0, 0);
    }
  };

  for (int chunk = 0; chunk < 4; ++chunk) {
    const int cn0 = chunk * 256;
    if (chunk == 0) stageA(0, 0);
    stageB(0, cn0, 0);
    stageQ(cn0, 0, 0);

    f32x4 z_acc[4][4];
#pragma unroll
    for (int i = 0; i < 4; ++i)
#pragma unroll
      for (int j = 0; j < 4; ++j) z_acc[i][j] = zero4;

    int cur = 0;
    for (int it = 0; it < 8; ++it) {
      __syncthreads();                  // buf[cur] staged; prior reads fenced
      if (it < 7) {
        stageB(cur ^ 1, cn0, (it + 1) * 64);
        stageA(cur ^ 1, (it + 1) * 64);
      }
      const bf16* lA = (const bf16*)(smem + cur * 16384);
      const bf16* lB = (const bf16*)(smem + 32768 + cur * 32768);
#pragma unroll
      for (int ks = 0; ks < 2; ++ks) {
        bf16x8 a[4], b[4];
#pragma unroll
        for (int t = 0; t < 4; ++t)
          a[t] = *(const bf16x8*)(lA + (am0 + t * 16 + lrow) * 64 +
                                  (((ks * 4 + quad) ^ lsw) * 8));
#pragma unroll
        for (int t = 0; t < 4; ++t)
          b[t] = *(const bf16x8*)(lB + (bn0 + t * 16 + lrow) * 64 +
                                  (((ks * 4 + quad) ^ lsw) * 8));
#pragma unroll
        for (int mi = 0; mi < 4; ++mi)
#pragma unroll
          for (int ni = 0; ni < 4; ++ni)
            z_acc[mi][ni] =
                __builtin_amdgcn_mfma_f32_16x16x32_bf16(a[mi], b[ni], z_acc[mi][ni], 0, 0, 0);
      }
      cur ^= 1;
    }

    __syncthreads();                    // (a) all K-loop reads fenced; B bufs dead
    stageQ(cn0, 1, 1);                  // w2 quarter 1 -> pp1 (under z-write)
#pragma unroll
    for (int mi = 0; mi < 4; ++mi) {
#pragma unroll
      for (int ni = 0; ni < 4; ++ni) {
        int zcol = bn0 + ni * 16 + lrow;
        float bv = b1[cn0 + zcol];
        int q5 = zcol >> 3;
#pragma unroll
        for (int r = 0; r < 4; ++r) {
          int zrow = am0 + mi * 16 + quad * 4 + r;
          float v = z_acc[mi][ni][r] + bv;
          v = v > 0.f ? v : 0.f;
          zbuf[zrow * 256 + ((q5 ^ bitswap02(zrow & 7)) << 3) + (zcol & 7)] = (bf16)v;
        }
      }
    }
    __syncthreads();                    // (b) z visible; q0/q1 staged
    layer3(0, 0);
    __syncthreads();                    // (c) pp0 reads done
    stageQ(cn0, 2, 0);                  // q2 -> pp0 (under layer3 q1)
    layer3(1, 1);
    __syncthreads();                    // (d) pp1 reads done; q2 landed
    stageQ(cn0, 3, 1);                  // q3 -> pp1 (under layer3 q2)
    if (chunk < 3) stageA(0, 0);        // prefetch next chunk's first A tile
    layer3(2, 0);
    __syncthreads();                    // (e) pp0 reads done; q3 + A landed
    layer3(3, 1);
    __syncthreads();                    // (f) all zbuf reads done -> next chunk
  }

  // epilogue: out = out_acc + b2
#pragma unroll
  for (int mi = 0; mi < 4; ++mi) {
#pragma unroll
    for (int ni = 0; ni < 2; ++ni) {
      int col = lb0 + ni * 16 + lrow;
      float bv = b2[col];
#pragma unroll
      for (int r = 0; r < 4; ++r) {
        int row = m0 + am0 + mi * 16 + quad * 4 + r;
        out[(size_t)row * LABELS + col] = out_acc[mi][ni][r] + bv;
      }
    }
  }
}

// ---- launcher --------------------------------------------------------------

extern "C" void kernel_launch(void* const* d_in, const int* in_sizes, int n_in,
                              void* d_out, int out_size, void* d_ws, size_t ws_size,
                              hipStream_t stream) {
  const int* tok = (const int*)d_in[0];
  const float* emb = (const float*)d_in[1];
  const float* conv_w = (const float*)d_in[2];  // [512,512] = [N,K]
  const float* conv_b = (const float*)d_in[3];
  const float* w1 = (const float*)d_in[4];      // [512,1024] = [K,N]
  const float* b1 = (const float*)d_in[5];
  const float* w2 = (const float*)d_in[6];      // [1024,128] = [K,N]
  const float* b2 = (const float*)d_in[7];
  float* out = (float*)d_out;

  char* ws = (char*)d_ws;
  bf16* wtc = (bf16*)(ws);                       // 512 KB [512,512]
  bf16* wt1 = (bf16*)(ws + (1u << 19));          // 1 MB   [1024,512]
  bf16* wt2 = (bf16*)(ws + 3 * (1u << 19));      // 256 KB [128,1024]
  bf16* h = (bf16*)(ws + (2u << 20));            // 32 MB  [32768,512]

  // weight prep
  hipLaunchKernelGGL(cvt_bf16, dim3(256), dim3(256), 0, stream,
                     conv_w, wtc, CONV_C * EMBED);
  hipLaunchKernelGGL(transpose_cvt, dim3(8, 16), dim3(256), 0, stream,
                     w1, wt1, CONV_C, HID);
  hipLaunchKernelGGL(transpose_cvt, dim3(16, 2), dim3(256), 0, stream,
                     w2, wt2, HID, LABELS);

  // layer 1 v2 (gather fused, 8-wave 128-row blocks, full-N per block)
  hipLaunchKernelGGL(gemm1_gather, dim3(NROWS / 128), dim3(512),
                     0, stream, tok, emb, wtc, conv_b, h, NROWS, CONV_C, EMBED);
  // layers 2+3 fused (v4: 128-row blocks, 8 waves, 64x64 wave tiles)
  hipLaunchKernelGGL(gemm23_fused, dim3(NROWS / 128), dim3(512),
                     0, stream, h, wt1, wt2, b1, b2, out);
}